// Round 4
// baseline (9570.535 us; speedup 1.0000x reference)
//
#include <hip/hip_runtime.h>
#include <stdint.h>

// Persistent dataflow 2-layer LSTM, MI355X (gfx950).
// 64 WGs x 256 thr: WGs 0..31 = layer0 (16 h-cols each), 32..63 = layer1.
// Sync: per-step aggregated counters (one 64B line per step). Producers do
// one fire-and-forget atomicAdd after draining their sc1 ring stores;
// consumers poll ONE word with all 64 lanes at the same address (coalesces
// to one request per wave per poll), prefetched at the top of the step so
// the flag-independent MFMAs hide the IC round trip. Rings are write-once.
// Weights fp32->bf16 once, held entirely in VGPRs.
// HANG-PROOF: per-thread global spin budget; on exhaustion waits no-op.

#define SEQ   1024
#define NB    32
#define HID   512
#define NWG   64
#define L0WGS 32
#define FSTRIDE 16              // flag words per step (64B line isolation)
#define SPIN_BUDGET (1 << 20)

typedef __attribute__((ext_vector_type(8))) short s16x8;
typedef __attribute__((ext_vector_type(4))) float f32x4;

__device__ __forceinline__ uint16_t f2bf(float x) {
    uint32_t u = __float_as_uint(x);
    return (uint16_t)((u + 0x7FFFu + ((u >> 16) & 1u)) >> 16);
}
__device__ __forceinline__ uint32_t pack2bf(float a, float b) {
    return (uint32_t)f2bf(a) | ((uint32_t)f2bf(b) << 16);
}
__device__ __forceinline__ s16x8 pack8(const float* p) {
    float4 a = *(const float4*)p;
    float4 b = *(const float4*)(p + 4);
    s16x8 r;
    r[0] = (short)f2bf(a.x); r[1] = (short)f2bf(a.y);
    r[2] = (short)f2bf(a.z); r[3] = (short)f2bf(a.w);
    r[4] = (short)f2bf(b.x); r[5] = (short)f2bf(b.y);
    r[6] = (short)f2bf(b.z); r[7] = (short)f2bf(b.w);
    return r;
}
__device__ __forceinline__ f32x4 mfma16(s16x8 a, s16x8 b, f32x4 c) {
    return __builtin_amdgcn_mfma_f32_16x16x32_bf16(a, b, c, 0, 0, 0);
}
__device__ __forceinline__ float sigm(float x) { return 1.0f / (1.0f + __expf(-x)); }
__device__ __forceinline__ float tanh_(float x) { return 1.0f - 2.0f / (__expf(2.0f * x) + 1.0f); }

__device__ __forceinline__ void st_u32(uint32_t* p, uint32_t v) {
    __hip_atomic_store(p, v, __ATOMIC_RELAXED, __HIP_MEMORY_SCOPE_AGENT);
}
__device__ __forceinline__ void st_u64(uint64_t* p, uint64_t v) {
    __hip_atomic_store(p, v, __ATOMIC_RELAXED, __HIP_MEMORY_SCOPE_AGENT);
}
__device__ __forceinline__ unsigned ld_flag(const unsigned* p) {
    return __hip_atomic_load(p, __ATOMIC_RELAXED, __HIP_MEMORY_SCOPE_AGENT);
}
// Spin until *p >= target. `first` is a prefetched sample (may be stale).
// All 64 lanes load the same word -> one request per wave per poll.
__device__ __forceinline__ void poll_ctr(const unsigned* p, unsigned target,
                                         unsigned first, int& budget) {
    unsigned v = first;
    while (v < target) {
        if (--budget < 0) break;          // hang-proof: give up, free-run
        __builtin_amdgcn_s_sleep(2);
        v = ld_flag(p);
    }
    asm volatile("" ::: "memory");        // ring loads stay below the poll
}

struct Shared {
    float gbuf[4][NB][16];
    float cbuf[NB][16];
    float bbuf[4][16];
};

__device__ __forceinline__ void load_bias_c(Shared& sh,
        const float* bf_, const float* bi_, const float* bc_, const float* bo_,
        int col0) {
    const int tid = threadIdx.x;
    if (tid < 16)       sh.bbuf[0][tid]      = bf_[col0 + tid];
    else if (tid < 32)  sh.bbuf[1][tid - 16] = bi_[col0 + tid - 16];
    else if (tid < 48)  sh.bbuf[2][tid - 32] = bc_[col0 + tid - 32];
    else if (tid < 64)  sh.bbuf[3][tid - 48] = bo_[col0 + tid - 48];
    ((float2*)sh.cbuf)[tid] = make_float2(0.f, 0.f);
}

__device__ __forceinline__ float2 gates2(Shared& sh, int b, int n) {
    float2 pf = *(float2*)&sh.gbuf[0][b][n];
    float2 pi = *(float2*)&sh.gbuf[1][b][n];
    float2 pc = *(float2*)&sh.gbuf[2][b][n];
    float2 po = *(float2*)&sh.gbuf[3][b][n];
    float2 h;
    {
        float f = sigm(pf.x + sh.bbuf[0][n]);
        float i = sigm(pi.x + sh.bbuf[1][n]);
        float g = tanh_(pc.x + sh.bbuf[2][n]);
        float o = sigm(po.x + sh.bbuf[3][n]);
        float c = f * sh.cbuf[b][n] + i * g;
        sh.cbuf[b][n] = c;
        h.x = o * tanh_(c);
    }
    {
        float f = sigm(pf.y + sh.bbuf[0][n + 1]);
        float i = sigm(pi.y + sh.bbuf[1][n + 1]);
        float g = tanh_(pc.y + sh.bbuf[2][n + 1]);
        float o = sigm(po.y + sh.bbuf[3][n + 1]);
        float c = f * sh.cbuf[b][n + 1] + i * g;
        sh.cbuf[b][n + 1] = c;
        h.y = o * tanh_(c);
    }
    return h;
}

__device__ void body_l0(const float* __restrict__ xg,
                        const float* __restrict__ Wf, const float* __restrict__ Wi,
                        const float* __restrict__ Wc, const float* __restrict__ Wo,
                        const float* __restrict__ bf_, const float* __restrict__ bi_,
                        const float* __restrict__ bc_, const float* __restrict__ bo_,
                        uint16_t* __restrict__ ring0, unsigned* __restrict__ flags0,
                        int w)
{
    const int tid  = threadIdx.x;
    const int wave = tid >> 6;
    const int lane = tid & 63;
    const int nloc = lane & 15;
    const int quad = lane >> 4;
    const int col0 = w * 16;
    int budget = SPIN_BUDGET;

    __shared__ Shared sh;
    load_bias_c(sh, bf_, bi_, bc_, bo_, col0);

    const float* Wg = (wave == 0) ? Wf : (wave == 1) ? Wi : (wave == 2) ? Wc : Wo;
    const float* wrow = Wg + (size_t)(col0 + nloc) * 768 + quad * 8;
    s16x8 B[24];
#pragma unroll
    for (int kt = 0; kt < 24; ++kt) B[kt] = pack8(wrow + kt * 32);

    uint32_t* ring0w = (uint32_t*)ring0;
    __syncthreads();

#pragma unroll 1
    for (int t = 0; t < SEQ; ++t) {
        // Prefetch the dependency counter sample first (in flight during x-part)
        const unsigned* f0p = &flags0[(size_t)(t > 0 ? t - 1 : 0) * FSTRIDE];
        unsigned pre = ld_flag(f0p);

        f32x4 acc0 = {0.f, 0.f, 0.f, 0.f};
        f32x4 acc1 = {0.f, 0.f, 0.f, 0.f};
        {   // x(t) part: independent of flags
            const float* px0 = xg + ((size_t)nloc * SEQ + t) * 256 + quad * 8;
            const float* px1 = px0 + (size_t)16 * SEQ * 256;
#pragma unroll
            for (int kt = 0; kt < 8; ++kt) {
                acc0 = mfma16(pack8(px0 + kt * 32), B[kt], acc0);
                acc1 = mfma16(pack8(px1 + kt * 32), B[kt], acc1);
            }
        }
        if (t > 0) {
            poll_ctr(f0p, L0WGS, pre, budget);
            const uint16_t* ph0 = ring0 + ((size_t)(t - 1) * NB + nloc) * HID + quad * 8;
#pragma unroll
            for (int kt = 0; kt < 16; ++kt) {
                s16x8 a0 = *(const s16x8*)(ph0 + kt * 32);
                s16x8 a1 = *(const s16x8*)(ph0 + 16 * HID + kt * 32);
                acc0 = mfma16(a0, B[8 + kt], acc0);
                acc1 = mfma16(a1, B[8 + kt], acc1);
            }
        }
#pragma unroll
        for (int r = 0; r < 4; ++r) {
            sh.gbuf[wave][quad * 4 + r][nloc]      = acc0[r];
            sh.gbuf[wave][16 + quad * 4 + r][nloc] = acc1[r];
        }
        __syncthreads();
        {
            const int b = tid >> 3, n = (tid & 7) * 2;
            float2 h = gates2(sh, b, n);
            st_u32(ring0w + ((size_t)t * NB + b) * (HID / 2) + (col0 + n) / 2,
                   pack2bf(h.x, h.y));
        }
        __syncthreads();              // all waves' sc1 stores drained (vmcnt 0)
        if (tid == 0) atomicAdd(&flags0[(size_t)t * FSTRIDE], 1u);
    }
}

template<bool R1>
__device__ void body_l1(const float* __restrict__ Wf, const float* __restrict__ Wi,
                        const float* __restrict__ Wc, const float* __restrict__ Wo,
                        const float* __restrict__ bf_, const float* __restrict__ bi_,
                        const float* __restrict__ bc_, const float* __restrict__ bo_,
                        float* __restrict__ out,
                        uint16_t* __restrict__ ring0, uint16_t* __restrict__ ring1,
                        unsigned* __restrict__ flags0, unsigned* __restrict__ flags1,
                        int w)
{
    const int tid  = threadIdx.x;
    const int wave = tid >> 6;
    const int lane = tid & 63;
    const int nloc = lane & 15;
    const int quad = lane >> 4;
    const int col0 = w * 16;
    int budget = SPIN_BUDGET;

    __shared__ Shared sh;
    load_bias_c(sh, bf_, bi_, bc_, bo_, col0);

    const float* Wg = (wave == 0) ? Wf : (wave == 1) ? Wi : (wave == 2) ? Wc : Wo;
    const float* wrow = Wg + (size_t)(col0 + nloc) * 1024 + quad * 8;
    s16x8 B[32];
#pragma unroll
    for (int kt = 0; kt < 32; ++kt) B[kt] = pack8(wrow + kt * 32);

    uint32_t* ring1w = (uint32_t*)ring1;
    __syncthreads();

#pragma unroll 1
    for (int t = 0; t < SEQ; ++t) {
        // Prefetch both dependency counters up front.
        const unsigned* f1p = &flags1[(size_t)(t > 0 ? t - 1 : 0) * FSTRIDE];
        const unsigned* f0p = &flags0[(size_t)t * FSTRIDE];
        unsigned pre1 = ld_flag(f1p);
        unsigned pre0 = ld_flag(f0p);

        f32x4 acc0 = {0.f, 0.f, 0.f, 0.f};
        f32x4 acc1 = {0.f, 0.f, 0.f, 0.f};
        // Own-chain recurrence first: h1(t-1) is the critical dependency.
        if (t > 0) {
            poll_ctr(f1p, L0WGS, pre1, budget);
            if (R1) {
                const uint16_t* ph1 = ring1 + ((size_t)(t - 1) * NB + nloc) * HID + quad * 8;
#pragma unroll
                for (int kt = 0; kt < 16; ++kt) {
                    s16x8 a0 = *(const s16x8*)(ph1 + kt * 32);
                    s16x8 a1 = *(const s16x8*)(ph1 + 16 * HID + kt * 32);
                    acc0 = mfma16(a0, B[16 + kt], acc0);
                    acc1 = mfma16(a1, B[16 + kt], acc1);
                }
            } else {
                const float* po0 = out + ((size_t)nloc * SEQ + (t - 1)) * HID + quad * 8;
                const float* po1 = po0 + (size_t)16 * SEQ * HID;
#pragma unroll
                for (int kt = 0; kt < 16; ++kt) {
                    acc0 = mfma16(pack8(po0 + kt * 32), B[16 + kt], acc0);
                    acc1 = mfma16(pack8(po1 + kt * 32), B[16 + kt], acc1);
                }
            }
        }
        // h0(t): L0 runs ahead, normally already set (poll was prefetched).
        poll_ctr(f0p, L0WGS, pre0, budget);
        {
            const uint16_t* ph0 = ring0 + ((size_t)t * NB + nloc) * HID + quad * 8;
#pragma unroll
            for (int kt = 0; kt < 16; ++kt) {
                s16x8 a0 = *(const s16x8*)(ph0 + kt * 32);
                s16x8 a1 = *(const s16x8*)(ph0 + 16 * HID + kt * 32);
                acc0 = mfma16(a0, B[kt], acc0);
                acc1 = mfma16(a1, B[kt], acc1);
            }
        }
#pragma unroll
        for (int r = 0; r < 4; ++r) {
            sh.gbuf[wave][quad * 4 + r][nloc]      = acc0[r];
            sh.gbuf[wave][16 + quad * 4 + r][nloc] = acc1[r];
        }
        __syncthreads();
        {
            const int b = tid >> 3, n = (tid & 7) * 2;
            float2 h = gates2(sh, b, n);
            float* po = &out[((size_t)b * SEQ + t) * HID + col0 + n];
            if (R1) {
                *(float2*)po = h;    // harness-only; flushed at kernel end
                st_u32(ring1w + ((size_t)t * NB + b) * (HID / 2) + (col0 + n) / 2,
                       pack2bf(h.x, h.y));
            } else {
                uint64_t v = (uint64_t)__float_as_uint(h.x)
                           | ((uint64_t)__float_as_uint(h.y) << 32);
                st_u64((uint64_t*)po, v);   // coherent: consumed next step
            }
        }
        __syncthreads();
        if (tid == 0) atomicAdd(&flags1[(size_t)t * FSTRIDE], 1u);
    }
}

template<bool R1>
__global__ __launch_bounds__(256, 1) void lstm_k(
    const float* __restrict__ x,
    const float* W0f, const float* b0f, const float* W0i, const float* b0i,
    const float* W0c, const float* b0c, const float* W0o, const float* b0o,
    const float* W1f, const float* b1f, const float* W1i, const float* b1i,
    const float* W1c, const float* b1c, const float* W1o, const float* b1o,
    float* out, uint16_t* ring0, uint16_t* ring1,
    unsigned* flags0, unsigned* flags1)
{
    if (blockIdx.x < L0WGS)
        body_l0(x, W0f, W0i, W0c, W0o, b0f, b0i, b0c, b0o,
                ring0, flags0, blockIdx.x);
    else
        body_l1<R1>(W1f, W1i, W1c, W1o, b1f, b1i, b1c, b1o,
                    out, ring0, ring1, flags0, flags1, blockIdx.x - L0WGS);
}

extern "C" void kernel_launch(void* const* d_in, const int* in_sizes, int n_in,
                              void* d_out, int out_size, void* d_ws, size_t ws_size,
                              hipStream_t stream) {
    const float* x   = (const float*)d_in[0];
    const float* W0f = (const float*)d_in[1];  const float* b0f = (const float*)d_in[2];
    const float* W0i = (const float*)d_in[3];  const float* b0i = (const float*)d_in[4];
    const float* W0c = (const float*)d_in[5];  const float* b0c = (const float*)d_in[6];
    const float* W0o = (const float*)d_in[7];  const float* b0o = (const float*)d_in[8];
    const float* W1f = (const float*)d_in[9];  const float* b1f = (const float*)d_in[10];
    const float* W1i = (const float*)d_in[11]; const float* b1i = (const float*)d_in[12];
    const float* W1c = (const float*)d_in[13]; const float* b1c = (const float*)d_in[14];
    const float* W1o = (const float*)d_in[15]; const float* b1o = (const float*)d_in[16];
    float* out = (float*)d_out;

    const size_t flag_bytes = (size_t)SEQ * FSTRIDE * 4;     // 64 KiB each
    const size_t ring_bytes = (size_t)SEQ * NB * HID * 2;    // 32 MiB each
    unsigned* flags0 = (unsigned*)d_ws;
    unsigned* flags1 = flags0 + SEQ * FSTRIDE;
    uint16_t* ring0  = (uint16_t*)((char*)d_ws + 2 * flag_bytes);
    uint16_t* ring1  = (uint16_t*)((char*)d_ws + 2 * flag_bytes + ring_bytes);
    const bool use_r1 = ws_size >= 2 * flag_bytes + 2 * ring_bytes;

    hipMemsetAsync(d_ws, 0, 2 * flag_bytes, stream);   // zero all counters

    if (use_r1)
        hipLaunchKernelGGL(lstm_k<true>, dim3(NWG), dim3(256), 0, stream,
            x, W0f, b0f, W0i, b0i, W0c, b0c, W0o, b0o,
            W1f, b1f, W1i, b1i, W1c, b1c, W1o, b1o,
            out, ring0, ring1, flags0, flags1);
    else
        hipLaunchKernelGGL(lstm_k<false>, dim3(NWG), dim3(256), 0, stream,
            x, W0f, b0f, W0i, b0i, W0c, b0c, W0o, b0o,
            W1f, b1f, W1i, b1i, W1c, b1c, W1o, b1o,
            out, ring0, ring1, flags0, flags1);
}

// Round 5
// 6020.129 us; speedup vs baseline: 1.5898x; 1.5898x over previous
//
#include <hip/hip_runtime.h>
#include <stdint.h>

// Persistent dataflow 2-layer LSTM, MI355X (gfx950).
// 64 WGs x 256 thr: WGs 0..31 = layer0 (16 h-cols each), 32..63 = layer1.
// Round-5: A-operand staging (h rings, x tile) via global_load_lds async DMA
// (no VGPR round trip -> loads fully pipelined, ~1 IC latency per step
// instead of 4-8 serialized ones under B[]-register pressure); MFMA fed by
// ds_read_b128 from padded LDS rows. Weights stay in VGPRs. Sync: per-step
// aggregated counters (atomicAdd publish, one-word all-lane poll).
// HANG-PROOF: per-thread global spin budget; on exhaustion waits no-op.

#define SEQ   1024
#define NB    32
#define HID   512
#define NWG   64
#define L0WGS 32
#define FSTRIDE 16                // flag words per step (64B line isolation)
#define SPIN_BUDGET (1 << 20)
#define ROWB  1040                // LDS row stride: 1024 data + 16 pad
#define SMEM_MISC 10496           // sizeof(Shared)
#define SMEM_BYTES (SMEM_MISC + 2 * 32 * ROWB)   // 77056

typedef __attribute__((ext_vector_type(8))) short s16x8;
typedef __attribute__((ext_vector_type(4))) float f32x4;

__device__ __forceinline__ uint16_t f2bf(float x) {
    uint32_t u = __float_as_uint(x);
    return (uint16_t)((u + 0x7FFFu + ((u >> 16) & 1u)) >> 16);
}
__device__ __forceinline__ uint32_t pack2bf(float a, float b) {
    return (uint32_t)f2bf(a) | ((uint32_t)f2bf(b) << 16);
}
__device__ __forceinline__ s16x8 pack8(const float* p) {
    float4 a = *(const float4*)p;
    float4 b = *(const float4*)(p + 4);
    s16x8 r;
    r[0] = (short)f2bf(a.x); r[1] = (short)f2bf(a.y);
    r[2] = (short)f2bf(a.z); r[3] = (short)f2bf(a.w);
    r[4] = (short)f2bf(b.x); r[5] = (short)f2bf(b.y);
    r[6] = (short)f2bf(b.z); r[7] = (short)f2bf(b.w);
    return r;
}
__device__ __forceinline__ f32x4 mfma16(s16x8 a, s16x8 b, f32x4 c) {
    return __builtin_amdgcn_mfma_f32_16x16x32_bf16(a, b, c, 0, 0, 0);
}
__device__ __forceinline__ float sigm(float x) { return 1.0f / (1.0f + __expf(-x)); }
__device__ __forceinline__ float tanh_(float x) { return 1.0f - 2.0f / (__expf(2.0f * x) + 1.0f); }

__device__ __forceinline__ void st_u32(uint32_t* p, uint32_t v) {
    __hip_atomic_store(p, v, __ATOMIC_RELAXED, __HIP_MEMORY_SCOPE_AGENT);
}
__device__ __forceinline__ void st_u64(uint64_t* p, uint64_t v) {
    __hip_atomic_store(p, v, __ATOMIC_RELAXED, __HIP_MEMORY_SCOPE_AGENT);
}
__device__ __forceinline__ unsigned ld_flag(const unsigned* p) {
    return __hip_atomic_load(p, __ATOMIC_RELAXED, __HIP_MEMORY_SCOPE_AGENT);
}
// All 64 lanes load the same word -> one request per wave per poll.
__device__ __forceinline__ void poll(const unsigned* p, unsigned target, int& budget) {
    while (ld_flag(p) < target) {
        if (--budget < 0) break;          // hang-proof: give up, free-run
        __builtin_amdgcn_s_sleep(1);
    }
    asm volatile("" ::: "memory");        // ring reads stay below the poll
}

// Async global->LDS DMA, 16B/lane. LDS dest = wave-uniform base + lane*16.
__device__ __forceinline__ void dma16(const void* g, void* l) {
    __builtin_amdgcn_global_load_lds(
        (const __attribute__((address_space(1))) unsigned int*)g,
        (__attribute__((address_space(3))) unsigned int*)l, 16, 0, 0);
}
// Stage 32 rows of 1024B into LDS rows of stride ROWB; wave wv does 8 rows.
__device__ __forceinline__ void stage32(const char* gbase, size_t gstride,
                                        char* lbase, int lane, int wv) {
#pragma unroll
    for (int i = 0; i < 8; ++i) {
        const int r = wv * 8 + i;
        dma16(gbase + (size_t)r * gstride + (size_t)lane * 16, lbase + r * ROWB);
    }
}

struct Shared {
    float gbuf[4][NB][16];
    float cbuf[NB][16];
    float bbuf[4][16];
};

__device__ __forceinline__ void load_bias_c(Shared& sh,
        const float* bf_, const float* bi_, const float* bc_, const float* bo_,
        int col0) {
    const int tid = threadIdx.x;
    if (tid < 16)       sh.bbuf[0][tid]      = bf_[col0 + tid];
    else if (tid < 32)  sh.bbuf[1][tid - 16] = bi_[col0 + tid - 16];
    else if (tid < 48)  sh.bbuf[2][tid - 32] = bc_[col0 + tid - 32];
    else if (tid < 64)  sh.bbuf[3][tid - 48] = bo_[col0 + tid - 48];
    ((float2*)sh.cbuf)[tid] = make_float2(0.f, 0.f);
}

__device__ __forceinline__ float2 gates2(Shared& sh, int b, int n) {
    float2 pf = *(float2*)&sh.gbuf[0][b][n];
    float2 pi = *(float2*)&sh.gbuf[1][b][n];
    float2 pc = *(float2*)&sh.gbuf[2][b][n];
    float2 po = *(float2*)&sh.gbuf[3][b][n];
    float2 h;
    {
        float f = sigm(pf.x + sh.bbuf[0][n]);
        float i = sigm(pi.x + sh.bbuf[1][n]);
        float g = tanh_(pc.x + sh.bbuf[2][n]);
        float o = sigm(po.x + sh.bbuf[3][n]);
        float c = f * sh.cbuf[b][n] + i * g;
        sh.cbuf[b][n] = c;
        h.x = o * tanh_(c);
    }
    {
        float f = sigm(pf.y + sh.bbuf[0][n + 1]);
        float i = sigm(pi.y + sh.bbuf[1][n + 1]);
        float g = tanh_(pc.y + sh.bbuf[2][n + 1]);
        float o = sigm(po.y + sh.bbuf[3][n + 1]);
        float c = f * sh.cbuf[b][n + 1] + i * g;
        sh.cbuf[b][n + 1] = c;
        h.y = o * tanh_(c);
    }
    return h;
}

extern __shared__ char smem[];

__device__ void body_l0(const float* __restrict__ xg,
                        const float* __restrict__ Wf, const float* __restrict__ Wi,
                        const float* __restrict__ Wc, const float* __restrict__ Wo,
                        const float* __restrict__ bf_, const float* __restrict__ bi_,
                        const float* __restrict__ bc_, const float* __restrict__ bo_,
                        uint16_t* __restrict__ ring0, unsigned* __restrict__ flags0,
                        int w)
{
    const int tid  = threadIdx.x;
    const int wave = tid >> 6;
    const int lane = tid & 63;
    const int nloc = lane & 15;
    const int quad = lane >> 4;
    const int col0 = w * 16;
    int budget = SPIN_BUDGET;

    Shared& sh = *(Shared*)smem;
    char* hbuf = smem + SMEM_MISC;            // h0(t-1) stage, 32 bf16 rows
    char* xbuf = hbuf + 32 * ROWB;            // x(t) stage, 32 fp32 rows
    load_bias_c(sh, bf_, bi_, bc_, bo_, col0);

    const float* Wg = (wave == 0) ? Wf : (wave == 1) ? Wi : (wave == 2) ? Wc : Wo;
    const float* wrow = Wg + (size_t)(col0 + nloc) * 768 + quad * 8;
    s16x8 B[24];
#pragma unroll
    for (int kt = 0; kt < 24; ++kt) B[kt] = pack8(wrow + kt * 32);

    uint32_t* ring0w = (uint32_t*)ring0;
    __syncthreads();

#pragma unroll 1
    for (int t = 0; t < SEQ; ++t) {
        // 1) Fire x(t) DMA (row b at (b*SEQ+t)*1024 bytes, stride SEQ*1024).
        stage32((const char*)xg + (size_t)t * 1024, (size_t)SEQ * 1024,
                xbuf, lane, wave);
        // 2) Own-chain h0(t-1): poll, then stage (rows at stride 1024B).
        if (t > 0) {
            poll(&flags0[(size_t)(t - 1) * FSTRIDE], L0WGS, budget);
            stage32((const char*)ring0 + (size_t)(t - 1) * 32768, 1024,
                    hbuf, lane, wave);
        }
        __builtin_amdgcn_s_waitcnt(0);   // all DMAs landed in LDS
        __syncthreads();

        f32x4 acc0 = {0.f, 0.f, 0.f, 0.f};
        f32x4 acc1 = {0.f, 0.f, 0.f, 0.f};
        {   // x-part from LDS (fp32 -> bf16 in-register)
            const char* pxl  = xbuf + nloc * ROWB + quad * 32;
            const char* pxl2 = pxl + 16 * ROWB;
#pragma unroll
            for (int kt = 0; kt < 8; ++kt) {
                acc0 = mfma16(pack8((const float*)(pxl  + kt * 128)), B[kt], acc0);
                acc1 = mfma16(pack8((const float*)(pxl2 + kt * 128)), B[kt], acc1);
            }
        }
        if (t > 0) {   // h-part from LDS (bf16)
            const char* ph  = hbuf + nloc * ROWB + quad * 16;
            const char* ph2 = ph + 16 * ROWB;
#pragma unroll
            for (int kt = 0; kt < 16; ++kt) {
                acc0 = mfma16(*(const s16x8*)(ph  + kt * 64), B[8 + kt], acc0);
                acc1 = mfma16(*(const s16x8*)(ph2 + kt * 64), B[8 + kt], acc1);
            }
        }
#pragma unroll
        for (int r = 0; r < 4; ++r) {
            sh.gbuf[wave][quad * 4 + r][nloc]      = acc0[r];
            sh.gbuf[wave][16 + quad * 4 + r][nloc] = acc1[r];
        }
        __syncthreads();
        {
            const int b = tid >> 3, n = (tid & 7) * 2;
            float2 h = gates2(sh, b, n);
            st_u32(ring0w + ((size_t)t * NB + b) * (HID / 2) + (col0 + n) / 2,
                   pack2bf(h.x, h.y));
        }
        __syncthreads();              // all waves' sc1 stores drained (vmcnt 0)
        if (tid == 0) atomicAdd(&flags0[(size_t)t * FSTRIDE], 1u);
    }
}

template<bool R1>
__device__ void body_l1(const float* __restrict__ Wf, const float* __restrict__ Wi,
                        const float* __restrict__ Wc, const float* __restrict__ Wo,
                        const float* __restrict__ bf_, const float* __restrict__ bi_,
                        const float* __restrict__ bc_, const float* __restrict__ bo_,
                        float* __restrict__ out,
                        uint16_t* __restrict__ ring0, uint16_t* __restrict__ ring1,
                        unsigned* __restrict__ flags0, unsigned* __restrict__ flags1,
                        int w)
{
    const int tid  = threadIdx.x;
    const int wave = tid >> 6;
    const int lane = tid & 63;
    const int nloc = lane & 15;
    const int quad = lane >> 4;
    const int col0 = w * 16;
    int budget = SPIN_BUDGET;

    Shared& sh = *(Shared*)smem;
    char* hbuf0 = smem + SMEM_MISC;           // h0(t) stage
    char* hbuf1 = hbuf0 + 32 * ROWB;          // h1(t-1) stage
    load_bias_c(sh, bf_, bi_, bc_, bo_, col0);

    const float* Wg = (wave == 0) ? Wf : (wave == 1) ? Wi : (wave == 2) ? Wc : Wo;
    const float* wrow = Wg + (size_t)(col0 + nloc) * 1024 + quad * 8;
    s16x8 B[32];
#pragma unroll
    for (int kt = 0; kt < 32; ++kt) B[kt] = pack8(wrow + kt * 32);

    uint32_t* ring1w = (uint32_t*)ring1;
    __syncthreads();

#pragma unroll 1
    for (int t = 0; t < SEQ; ++t) {
        // h0(t): L0 runs ahead -> usually ready; stage first.
        poll(&flags0[(size_t)t * FSTRIDE], L0WGS, budget);
        stage32((const char*)ring0 + (size_t)t * 32768, 1024, hbuf0, lane, wave);
        // Own-chain h1(t-1): the latency-critical dependency.
        if (t > 0) {
            poll(&flags1[(size_t)(t - 1) * FSTRIDE], L0WGS, budget);
            if (R1)
                stage32((const char*)ring1 + (size_t)(t - 1) * 32768, 1024,
                        hbuf1, lane, wave);
        }
        __builtin_amdgcn_s_waitcnt(0);
        __syncthreads();

        f32x4 acc0 = {0.f, 0.f, 0.f, 0.f};
        f32x4 acc1 = {0.f, 0.f, 0.f, 0.f};
        {   // h0-part
            const char* ph  = hbuf0 + nloc * ROWB + quad * 16;
            const char* ph2 = ph + 16 * ROWB;
#pragma unroll
            for (int kt = 0; kt < 16; ++kt) {
                acc0 = mfma16(*(const s16x8*)(ph  + kt * 64), B[kt], acc0);
                acc1 = mfma16(*(const s16x8*)(ph2 + kt * 64), B[kt], acc1);
            }
        }
        if (t > 0) {   // h1-part
            if (R1) {
                const char* ph  = hbuf1 + nloc * ROWB + quad * 16;
                const char* ph2 = ph + 16 * ROWB;
#pragma unroll
                for (int kt = 0; kt < 16; ++kt) {
                    acc0 = mfma16(*(const s16x8*)(ph  + kt * 64), B[16 + kt], acc0);
                    acc1 = mfma16(*(const s16x8*)(ph2 + kt * 64), B[16 + kt], acc1);
                }
            } else {
                const float* po0 = out + ((size_t)nloc * SEQ + (t - 1)) * HID + quad * 8;
                const float* po1 = po0 + (size_t)16 * SEQ * HID;
#pragma unroll
                for (int kt = 0; kt < 16; ++kt) {
                    acc0 = mfma16(pack8(po0 + kt * 32), B[16 + kt], acc0);
                    acc1 = mfma16(pack8(po1 + kt * 32), B[16 + kt], acc1);
                }
            }
        }
#pragma unroll
        for (int r = 0; r < 4; ++r) {
            sh.gbuf[wave][quad * 4 + r][nloc]      = acc0[r];
            sh.gbuf[wave][16 + quad * 4 + r][nloc] = acc1[r];
        }
        __syncthreads();
        {
            const int b = tid >> 3, n = (tid & 7) * 2;
            float2 h = gates2(sh, b, n);
            float* po = &out[((size_t)b * SEQ + t) * HID + col0 + n];
            if (R1) {
                *(float2*)po = h;    // harness-only; flushed at kernel end
                st_u32(ring1w + ((size_t)t * NB + b) * (HID / 2) + (col0 + n) / 2,
                       pack2bf(h.x, h.y));
            } else {
                uint64_t v = (uint64_t)__float_as_uint(h.x)
                           | ((uint64_t)__float_as_uint(h.y) << 32);
                st_u64((uint64_t*)po, v);   // coherent: consumed next step
            }
        }
        __syncthreads();
        if (tid == 0) atomicAdd(&flags1[(size_t)t * FSTRIDE], 1u);
    }
}

template<bool R1>
__global__ __launch_bounds__(256, 1) void lstm_k(
    const float* __restrict__ x,
    const float* W0f, const float* b0f, const float* W0i, const float* b0i,
    const float* W0c, const float* b0c, const float* W0o, const float* b0o,
    const float* W1f, const float* b1f, const float* W1i, const float* b1i,
    const float* W1c, const float* b1c, const float* W1o, const float* b1o,
    float* out, uint16_t* ring0, uint16_t* ring1,
    unsigned* flags0, unsigned* flags1)
{
    if (blockIdx.x < L0WGS)
        body_l0(x, W0f, W0i, W0c, W0o, b0f, b0i, b0c, b0o,
                ring0, flags0, blockIdx.x);
    else
        body_l1<R1>(W1f, W1i, W1c, W1o, b1f, b1i, b1c, b1o,
                    out, ring0, ring1, flags0, flags1, blockIdx.x - L0WGS);
}

extern "C" void kernel_launch(void* const* d_in, const int* in_sizes, int n_in,
                              void* d_out, int out_size, void* d_ws, size_t ws_size,
                              hipStream_t stream) {
    const float* x   = (const float*)d_in[0];
    const float* W0f = (const float*)d_in[1];  const float* b0f = (const float*)d_in[2];
    const float* W0i = (const float*)d_in[3];  const float* b0i = (const float*)d_in[4];
    const float* W0c = (const float*)d_in[5];  const float* b0c = (const float*)d_in[6];
    const float* W0o = (const float*)d_in[7];  const float* b0o = (const float*)d_in[8];
    const float* W1f = (const float*)d_in[9];  const float* b1f = (const float*)d_in[10];
    const float* W1i = (const float*)d_in[11]; const float* b1i = (const float*)d_in[12];
    const float* W1c = (const float*)d_in[13]; const float* b1c = (const float*)d_in[14];
    const float* W1o = (const float*)d_in[15]; const float* b1o = (const float*)d_in[16];
    float* out = (float*)d_out;

    const size_t flag_bytes = (size_t)SEQ * FSTRIDE * 4;     // 64 KiB each
    const size_t ring_bytes = (size_t)SEQ * NB * HID * 2;    // 32 MiB each
    unsigned* flags0 = (unsigned*)d_ws;
    unsigned* flags1 = flags0 + SEQ * FSTRIDE;
    uint16_t* ring0  = (uint16_t*)((char*)d_ws + 2 * flag_bytes);
    uint16_t* ring1  = (uint16_t*)((char*)d_ws + 2 * flag_bytes + ring_bytes);
    const bool use_r1 = ws_size >= 2 * flag_bytes + 2 * ring_bytes;

    hipFuncSetAttribute((const void*)lstm_k<true>,
                        hipFuncAttributeMaxDynamicSharedMemorySize, SMEM_BYTES);
    hipFuncSetAttribute((const void*)lstm_k<false>,
                        hipFuncAttributeMaxDynamicSharedMemorySize, SMEM_BYTES);

    hipMemsetAsync(d_ws, 0, 2 * flag_bytes, stream);   // zero all counters

    if (use_r1)
        hipLaunchKernelGGL(lstm_k<true>, dim3(NWG), dim3(256), SMEM_BYTES, stream,
            x, W0f, b0f, W0i, b0i, W0c, b0c, W0o, b0o,
            W1f, b1f, W1i, b1i, W1c, b1c, W1o, b1o,
            out, ring0, ring1, flags0, flags1);
    else
        hipLaunchKernelGGL(lstm_k<false>, dim3(NWG), dim3(256), SMEM_BYTES, stream,
            x, W0f, b0f, W0i, b0i, W0c, b0c, W0o, b0o,
            W1f, b1f, W1i, b1i, W1c, b1c, W1o, b1o,
            out, ring0, ring1, flags0, flags1);
}